// Round 4
// baseline (184.619 us; speedup 1.0000x reference)
//
#include <hip/hip_runtime.h>
#include <hip/hip_fp16.h>

// Problem constants (from reference):
//   x:    (B=2, C=8, F=80, N=128, N=128) fp32
//   quad: (H=512, W=1024) int32 in [0, F)
//   uv:   (H, W, 2) fp32 in [0, N-1)
//   out:  (B, C, H, W) fp32
#define BC   16                 // B*C
#define FD   80
#define ND   128
#define NN   (ND * ND)          // 16384
#define HW   (512 * 1024)       // 524288 = 2^19
#define HW_SHIFT 19

// v5 layout: y[f][v][u0] = 64 B entry {texel u0: ch0-15 fp16, texel u0+1: ch0-15}.
// Every gather touches exactly two 64B-ALIGNED chunks (no 128B-line straddle).
#define YH2_BYTES ((size_t)FD * ND * ND * 64)   // 83,886,080 (80 MB, L3-resident)

// Native clang vector types — required for __builtin_nontemporal_load/store
// (HIP_vector_type structs are rejected by the builtins).
typedef float vf4 __attribute__((ext_vector_type(4)));
typedef float vf2 __attribute__((ext_vector_type(2)));
typedef int   vi2 __attribute__((ext_vector_type(2)));

// ---------------------------------------------------------------------------
// Kernel 1: repack x[bc][f][v][u] (fp32) -> u-duplicated fp16 texture.
// Thread owns one u-quad (4 u) of one (f,v) row: 16 NT float4 loads (one per
// channel; each wave instr reads 2x512B contiguous), builds 4 output entries
// (the 4th needs neighbor's x[4q+4] -> one shfl per channel), stores 256 B
// contiguous. No LDS, no barriers.
// Block = 256 = 8 rows x 32 quads; grid = FD*ND/8 = 1280.
// ---------------------------------------------------------------------------
__global__ __launch_bounds__(256)
void repack_kernel(const float* __restrict__ x, __half* __restrict__ y)
{
    const int tid = threadIdx.x;
    const int q   = tid & 31;            // u-quad: u = 4q .. 4q+3
    const int r   = tid >> 5;            // row within block, 0..7
    const int fv  = blockIdx.x * 8 + r;  // global (f,v) row
    const int f   = fv >> 7;
    const int v   = fv & (ND - 1);

    const float* xp = x + ((size_t)f * ND + v) * ND + q * 4;
    vf4 g[BC];
#pragma unroll
    for (int c = 0; c < BC; ++c)
        g[c] = __builtin_nontemporal_load((const vf4*)(xp + (size_t)c * FD * NN));

    // Neighbor's first element = x[4q+4] per channel (lane q+1, same row).
    // q==31 -> entry 127 = (u=127, clamp(u+1)=127): use own .w. (Entry 127 is
    // never read by the gather since u0<=126, but keep it well-defined.)
    float xn[BC];
#pragma unroll
    for (int c = 0; c < BC; ++c) {
        const float s = __shfl_down(g[c].x, 1);
        xn[c] = (q == 31) ? g[c].w : s;
    }

    // Texel dwords: Ad[e][j] = half2(ch 2j, ch 2j+1) of texel u=4q+e.
    unsigned Ad[4][8], Bd[8];
#pragma unroll
    for (int e = 0; e < 4; ++e)
#pragma unroll
        for (int j = 0; j < 8; ++j) {
            const __half2 h = __floats2half2_rn(g[2 * j][e], g[2 * j + 1][e]);
            Ad[e][j] = *(const unsigned*)&h;
        }
#pragma unroll
    for (int j = 0; j < 8; ++j) {
        const __half2 h = __floats2half2_rn(xn[2 * j], xn[2 * j + 1]);
        Bd[j] = *(const unsigned*)&h;
    }

    // Entry e = [texel 4q+e ch0-15 | texel 4q+e+1 ch0-15] = 64 B.
    uint4* dst = (uint4*)(y + ((size_t)fv * ND + q * 4) * 32);
#pragma unroll
    for (int e = 0; e < 4; ++e) {
        const unsigned* Bp = (e < 3) ? Ad[e + 1] : Bd;
        dst[e * 4 + 0] = make_uint4(Ad[e][0], Ad[e][1], Ad[e][2], Ad[e][3]);
        dst[e * 4 + 1] = make_uint4(Ad[e][4], Ad[e][5], Ad[e][6], Ad[e][7]);
        dst[e * 4 + 2] = make_uint4(Bp[0], Bp[1], Bp[2], Bp[3]);
        dst[e * 4 + 3] = make_uint4(Bp[4], Bp[5], Bp[6], Bp[7]);
    }
}

// ---------------------------------------------------------------------------
// Kernel 2: gather. TWO pixels per thread, all 16 channels each.
// Per pixel: two 64B-aligned uint4x4 chunks (rows v0, v0+1 of the duplicated
// entry), no line straddle. Metadata as vf4/vi2 (one 16B + one 8B load per
// thread), outputs as 16 float2 NT stores (pixel-pair contiguous).
// ---------------------------------------------------------------------------
__device__ inline void acc8p(float2* o2, uint4 t, float w)
{
    const unsigned* p = (const unsigned*)&t;
#pragma unroll
    for (int j = 0; j < 4; ++j) {
        const float2 fp = __half22float2(*(const __half2*)&p[j]);
        o2[j].x += fp.x * w;
        o2[j].y += fp.y * w;
    }
}

__device__ inline void gather_one(const __half* __restrict__ y,
                                  float u, float v, int f, float2* o2)
{
    int u0 = (int)floorf(u);
    int v0 = (int)floorf(v);
    u0 = min(max(u0, 0), ND - 2);
    v0 = min(max(v0, 0), ND - 2);

    // entry (f, v0, u0): 64 B aligned; row stride = 128 entries = 512 uint4.
    const size_t entry = ((size_t)f * ND + v0) * ND + u0;
    const uint4* r0 = (const uint4*)(y + entry * 32);
    const uint4* r1 = r0 + 512;
    const uint4 a0 = r0[0], a1 = r0[1];   // (v0,  u0)   ch0-7, ch8-15
    const uint4 b0 = r0[2], b1 = r0[3];   // (v0,  u0+1)
    const uint4 c0 = r1[0], c1 = r1[1];   // (v0+1,u0)
    const uint4 d0 = r1[2], d1 = r1[3];   // (v0+1,u0+1)

    const float du = u - (float)u0;
    const float dv = v - (float)v0;
    const float w00 = (1.0f - du) * (1.0f - dv);
    const float w01 = du * (1.0f - dv);
    const float w10 = (1.0f - du) * dv;
    const float w11 = du * dv;

    acc8p(o2,     a0, w00); acc8p(o2 + 4, a1, w00);
    acc8p(o2,     b0, w01); acc8p(o2 + 4, b1, w01);
    acc8p(o2,     c0, w10); acc8p(o2 + 4, c1, w10);
    acc8p(o2,     d0, w11); acc8p(o2 + 4, d1, w11);
}

__global__ __launch_bounds__(256)
void gather_kernel(const __half* __restrict__ y,
                   const int*    __restrict__ quad,
                   const float2* __restrict__ uv2,
                   float* __restrict__ out)
{
    const int gid  = blockIdx.x * 256 + threadIdx.x;
    const int pix0 = gid * 2;

    const vf4 tv = __builtin_nontemporal_load((const vf4*)&uv2[pix0]);
    const vi2 ff = __builtin_nontemporal_load((const vi2*)&quad[pix0]);

    float2 oA[8], oB[8];
#pragma unroll
    for (int j = 0; j < 8; ++j) {
        oA[j] = make_float2(0.0f, 0.0f);
        oB[j] = make_float2(0.0f, 0.0f);
    }

    gather_one(y, tv.x, tv.y, ff.x, oA);
    gather_one(y, tv.z, tv.w, ff.y, oB);

    const float* a = (const float*)oA;
    const float* b = (const float*)oB;
#pragma unroll
    for (int c = 0; c < BC; ++c) {
        vf2 s; s.x = a[c]; s.y = b[c];
        __builtin_nontemporal_store(s, (vf2*)&out[(size_t)c * HW + pix0]);
    }
}

// ---------------------------------------------------------------------------
// Fallback: used only if ws_size can't hold the repacked texture.
// ---------------------------------------------------------------------------
__global__ __launch_bounds__(256)
void resample_fallback_kernel(const float* __restrict__ x,
                              const int*   __restrict__ quad,
                              const float2* __restrict__ uv2,
                              float* __restrict__ out)
{
    const int gid = blockIdx.x * 256 + threadIdx.x;
    const int pix = gid & (HW - 1);
    const int bc  = gid >> HW_SHIFT;

    const float2 t = uv2[pix];
    const int    f = quad[pix];

    const float u = t.x;
    const float v = t.y;

    int u0 = (int)floorf(u);
    int v0 = (int)floorf(v);
    u0 = min(max(u0, 0), ND - 2);
    v0 = min(max(v0, 0), ND - 2);

    const float du = u - (float)u0;
    const float dv = v - (float)v0;

    const float w00 = (1.0f - du) * (1.0f - dv);
    const float w01 = du * (1.0f - dv);
    const float w10 = (1.0f - du) * dv;
    const float w11 = du * dv;

    const float* p = x + ((size_t)bc * FD + (size_t)f) * NN + v0 * ND + u0;
    out[gid] = p[0] * w00 + p[1] * w01 + p[ND] * w10 + p[ND + 1] * w11;
}

extern "C" void kernel_launch(void* const* d_in, const int* in_sizes, int n_in,
                              void* d_out, int out_size, void* d_ws, size_t ws_size,
                              hipStream_t stream)
{
    const float*  x    = (const float*)d_in[0];
    const int*    quad = (const int*)d_in[1];
    const float2* uv2  = (const float2*)d_in[2];
    float*        out  = (float*)d_out;

    if (ws_size >= YH2_BYTES) {
        __half* y = (__half*)d_ws;
        repack_kernel<<<FD * ND / 8, 256, 0, stream>>>(x, y);          // 1280 blocks
        gather_kernel<<<HW / 512, 256, 0, stream>>>(y, quad, uv2, out); // 1024 blocks
    } else {
        const int total = BC * HW;
        resample_fallback_kernel<<<total / 256, 256, 0, stream>>>(x, quad, uv2, out);
    }
}

// Round 5
// 162.642 us; speedup vs baseline: 1.1351x; 1.1351x over previous
//
#include <hip/hip_runtime.h>
#include <hip/hip_fp16.h>

// Problem constants (from reference):
//   x:    (B=2, C=8, F=80, N=128, N=128) fp32
//   quad: (H=512, W=1024) int32 in [0, F)
//   uv:   (H, W, 2) fp32 in [0, N-1)
//   out:  (B, C, H, W) fp32
#define BC   16                 // B*C
#define FD   80
#define ND   128
#define NN   (ND * ND)          // 16384
#define HW   (512 * 1024)       // 524288 = 2^19
#define HW_SHIFT 19

#define YH_BYTES ((size_t)FD * NN * BC * sizeof(__half))   // 41,943,040 (42 MB)

// Native clang vector types — required for __builtin_nontemporal_load/store
// (HIP_vector_type structs are rejected by the builtins).
typedef float vf4 __attribute__((ext_vector_type(4)));
typedef float vf2 __attribute__((ext_vector_type(2)));

// ---------------------------------------------------------------------------
// Kernel 1: repack x[bc][f][v][u] (fp32) -> y[f][v][u][bc] (fp16, channels
// innermost). v6: v3's proven LDS structure (coalesced float4 NT loads,
// conflict-free float4 LDS layout, ONE dense uint4 store per thread per row
// -- wave stores 1 KB contiguous PER INSTRUCTION; v4/v5 showed strided
// partial-line stores leak to HBM with ~1.67x write amplification), but TWO
// (f,v) rows per block: all 4 loads issue before a single barrier (2x
// phase-1 MLP, half the barriers per byte). Grid = FD*ND/2 = 5120.
// ---------------------------------------------------------------------------
__global__ __launch_bounds__(256)
void repack_kernel(const float* __restrict__ x, __half* __restrict__ y)
{
    const int b2  = blockIdx.x;          // handles rows 2*b2, 2*b2+1
    const int tid = threadIdx.x;

    __shared__ vf4 lds4[2][32 * 17];     // [row][u4*17+c], 8704 B per row

    // Phase 1: 2 rows x 512 float4 loads (16 ch x 128 u each), coalesced
    // along u; all 4 per-thread loads in flight before the barrier.
#pragma unroll
    for (int rr = 0; rr < 2; ++rr) {
        const int fv = b2 * 2 + rr;
        const int f  = fv >> 7;
        const int v  = fv & (ND - 1);
#pragma unroll
        for (int r = 0; r < 2; ++r) {
            const int i4 = tid + r * 256;    // 0..511
            const int c  = i4 >> 5;          // 0..15
            const int u4 = i4 & 31;          // 0..31
            const vf4 val = __builtin_nontemporal_load(
                (const vf4*)(x + (((size_t)c * FD + f) * ND + v) * ND + u4 * 4));
            lds4[rr][u4 * 17 + c] = val;     // single ds_write_b128
        }
    }
    __syncthreads();

    // Phase 2: each thread packs 8 consecutive halves (16 B) per row.
    // float for (u, c) lives at word ((u>>2)*17 + c)*4 + (u&3);
    // bank = 4*(u>>2) + (u&3) + 4k is conflict-free (proven in v3).
    const int u  = tid >> 1;
    const int c0 = (tid & 1) * 8;
    const int w0 = ((u >> 2) * 17 + c0) * 4 + (u & 3);
#pragma unroll
    for (int rr = 0; rr < 2; ++rr) {
        const float* lf = (const float*)lds4[rr];
        uint4 rv;
        unsigned* rp = (unsigned*)&rv;
#pragma unroll
        for (int j = 0; j < 4; ++j) {
            const __half2 h = __floats2half2_rn(lf[w0 + (2 * j) * 4],
                                                lf[w0 + (2 * j + 1) * 4]);
            rp[j] = *(const unsigned*)&h;
        }
        // Wave writes 1 KB dense per instruction; block 4 KB per row.
        uint4* y4 = (uint4*)(y + (size_t)(b2 * 2 + rr) * ND * BC);
        y4[tid] = rv;
    }
}

// ---------------------------------------------------------------------------
// Kernel 2: gather. ONE thread per pixel, all 16 channels (proven v3 form).
// Per pixel: 2 NT metadata loads, 8 uint4 texel loads (the 64B v-row span
// (u0,u0+1)x16ch is fully consumed), 16 coalesced NT scalar stores (wave
// store = 256 B dense = 2 full lines per instruction).
// ---------------------------------------------------------------------------
__device__ inline void acc8p(float2* o2, uint4 t, float w)
{
    const unsigned* p = (const unsigned*)&t;
#pragma unroll
    for (int j = 0; j < 4; ++j) {
        const float2 fp = __half22float2(*(const __half2*)&p[j]);
        o2[j].x += fp.x * w;
        o2[j].y += fp.y * w;
    }
}

__global__ __launch_bounds__(256)
void gather_kernel(const __half* __restrict__ y,
                   const int*    __restrict__ quad,
                   const float2* __restrict__ uv2,
                   float* __restrict__ out)
{
    const int pix = blockIdx.x * 256 + threadIdx.x;

    const vf2 tv = __builtin_nontemporal_load((const vf2*)&uv2[pix]);
    const int f  = __builtin_nontemporal_load(&quad[pix]);

    const float u = tv.x;
    const float v = tv.y;

    int u0 = (int)floorf(u);
    int v0 = (int)floorf(v);
    u0 = min(max(u0, 0), ND - 2);
    v0 = min(max(v0, 0), ND - 2);

    // Issue all 8 texel loads (128 B, all consumed) before the weight math.
    const size_t base = (((size_t)f * ND + v0) * ND + u0) * BC;
    const uint4* r0 = (const uint4*)(y + base);                    // (v0,  u0..u0+1)
    const uint4* r1 = (const uint4*)(y + base + (size_t)ND * BC);  // (v0+1,u0..u0+1)
    const uint4 a0 = r0[0], a1 = r0[1];   // (v0,u0)   ch0-7, ch8-15
    const uint4 b0 = r0[2], b1 = r0[3];   // (v0,u0+1)
    const uint4 c0 = r1[0], c1 = r1[1];   // (v1,u0)
    const uint4 d0 = r1[2], d1 = r1[3];   // (v1,u0+1)

    const float du = u - (float)u0;
    const float dv = v - (float)v0;
    const float w00 = (1.0f - du) * (1.0f - dv);
    const float w01 = du * (1.0f - dv);
    const float w10 = (1.0f - du) * dv;
    const float w11 = du * dv;

    float2 o2[8];                        // ch pairs: o2[0..3]=ch0-7, o2[4..7]=ch8-15
#pragma unroll
    for (int j = 0; j < 8; ++j) o2[j] = make_float2(0.0f, 0.0f);

    acc8p(o2,     a0, w00); acc8p(o2 + 4, a1, w00);
    acc8p(o2,     b0, w01); acc8p(o2 + 4, b1, w01);
    acc8p(o2,     c0, w10); acc8p(o2 + 4, c1, w10);
    acc8p(o2,     d0, w11); acc8p(o2 + 4, d1, w11);

    // 16 coalesced scalar stores (64 consecutive pixels per wave per plane).
    const float* o = (const float*)o2;
#pragma unroll
    for (int c = 0; c < BC; ++c)
        __builtin_nontemporal_store(o[c], &out[(size_t)c * HW + pix]);
}

// ---------------------------------------------------------------------------
// Fallback: used only if ws_size can't hold the repacked texture.
// ---------------------------------------------------------------------------
__global__ __launch_bounds__(256)
void resample_fallback_kernel(const float* __restrict__ x,
                              const int*   __restrict__ quad,
                              const float2* __restrict__ uv2,
                              float* __restrict__ out)
{
    const int gid = blockIdx.x * 256 + threadIdx.x;
    const int pix = gid & (HW - 1);
    const int bc  = gid >> HW_SHIFT;

    const float2 t = uv2[pix];
    const int    f = quad[pix];

    const float u = t.x;
    const float v = t.y;

    int u0 = (int)floorf(u);
    int v0 = (int)floorf(v);
    u0 = min(max(u0, 0), ND - 2);
    v0 = min(max(v0, 0), ND - 2);

    const float du = u - (float)u0;
    const float dv = v - (float)v0;

    const float w00 = (1.0f - du) * (1.0f - dv);
    const float w01 = du * (1.0f - dv);
    const float w10 = (1.0f - du) * dv;
    const float w11 = du * dv;

    const float* p = x + ((size_t)bc * FD + (size_t)f) * NN + v0 * ND + u0;
    out[gid] = p[0] * w00 + p[1] * w01 + p[ND] * w10 + p[ND + 1] * w11;
}

extern "C" void kernel_launch(void* const* d_in, const int* in_sizes, int n_in,
                              void* d_out, int out_size, void* d_ws, size_t ws_size,
                              hipStream_t stream)
{
    const float*  x    = (const float*)d_in[0];
    const int*    quad = (const int*)d_in[1];
    const float2* uv2  = (const float2*)d_in[2];
    float*        out  = (float*)d_out;

    if (ws_size >= YH_BYTES) {
        __half* y = (__half*)d_ws;
        repack_kernel<<<FD * ND / 2, 256, 0, stream>>>(x, y);            // 5120 blocks
        gather_kernel<<<HW / 256, 256, 0, stream>>>(y, quad, uv2, out);  // 2048 blocks
    } else {
        const int total = BC * HW;
        resample_fallback_kernel<<<total / 256, 256, 0, stream>>>(x, quad, uv2, out);
    }
}

// Round 6
// 161.533 us; speedup vs baseline: 1.1429x; 1.0069x over previous
//
#include <hip/hip_runtime.h>
#include <hip/hip_fp16.h>

// Problem constants (from reference):
//   x:    (B=2, C=8, F=80, N=128, N=128) fp32
//   quad: (H=512, W=1024) int32 in [0, F)
//   uv:   (H, W, 2) fp32 in [0, N-1)
//   out:  (B, C, H, W) fp32
#define BC   16                 // B*C
#define FD   80
#define ND   128
#define NN   (ND * ND)          // 16384
#define HW   (512 * 1024)       // 524288 = 2^19
#define HW_SHIFT 19

#define YH_BYTES ((size_t)FD * NN * BC * sizeof(__half))   // 41,943,040 (42 MB)

// Native clang vector types — required for __builtin_nontemporal_load/store
// (HIP_vector_type structs are rejected by the builtins).
typedef float vf4 __attribute__((ext_vector_type(4)));
typedef float vf2 __attribute__((ext_vector_type(2)));

// ---------------------------------------------------------------------------
// Kernel 1: repack x[bc][f][v][u] (fp32) -> y[f][v][u][bc] (fp16, channels
// innermost). v6 structure (best measured): coalesced float4 NT loads,
// conflict-free float4 LDS layout, ONE dense uint4 store per thread per row
// (wave stores 1 KB contiguous PER INSTRUCTION; v4/v5 showed strided
// partial-line stores leak to HBM with ~1.67x write amplification). TWO
// (f,v) rows per block: all 4 loads issue before a single barrier.
// Grid = FD*ND/2 = 5120.
// ---------------------------------------------------------------------------
__global__ __launch_bounds__(256)
void repack_kernel(const float* __restrict__ x, __half* __restrict__ y)
{
    const int b2  = blockIdx.x;          // handles rows 2*b2, 2*b2+1
    const int tid = threadIdx.x;

    __shared__ vf4 lds4[2][32 * 17];     // [row][u4*17+c], 8704 B per row

    // Phase 1: 2 rows x 512 float4 loads (16 ch x 128 u each), coalesced
    // along u; all 4 per-thread loads in flight before the barrier.
#pragma unroll
    for (int rr = 0; rr < 2; ++rr) {
        const int fv = b2 * 2 + rr;
        const int f  = fv >> 7;
        const int v  = fv & (ND - 1);
#pragma unroll
        for (int r = 0; r < 2; ++r) {
            const int i4 = tid + r * 256;    // 0..511
            const int c  = i4 >> 5;          // 0..15
            const int u4 = i4 & 31;          // 0..31
            const vf4 val = __builtin_nontemporal_load(
                (const vf4*)(x + (((size_t)c * FD + f) * ND + v) * ND + u4 * 4));
            lds4[rr][u4 * 17 + c] = val;     // single ds_write_b128
        }
    }
    __syncthreads();

    // Phase 2: each thread packs 8 consecutive halves (16 B) per row.
    // float for (u, c) lives at word ((u>>2)*17 + c)*4 + (u&3);
    // bank = 4*(u>>2) + (u&3) + 4k is conflict-free (proven in v3).
    const int u  = tid >> 1;
    const int c0 = (tid & 1) * 8;
    const int w0 = ((u >> 2) * 17 + c0) * 4 + (u & 3);
#pragma unroll
    for (int rr = 0; rr < 2; ++rr) {
        const float* lf = (const float*)lds4[rr];
        uint4 rv;
        unsigned* rp = (unsigned*)&rv;
#pragma unroll
        for (int j = 0; j < 4; ++j) {
            const __half2 h = __floats2half2_rn(lf[w0 + (2 * j) * 4],
                                                lf[w0 + (2 * j + 1) * 4]);
            rp[j] = *(const unsigned*)&h;
        }
        // Wave writes 1 KB dense per instruction; block 4 KB per row.
        uint4* y4 = (uint4*)(y + (size_t)(b2 * 2 + rr) * ND * BC);
        y4[tid] = rv;
    }
}

// ---------------------------------------------------------------------------
// Kernel 2: gather. v7: TWO threads per pixel, 8 channels each.
// Rationale: 1 px/thread gave exactly 32 waves/CU (zero oversubscription);
// the post-poison L3 flush makes y-reads HBM-miss (~900 cyc), so the
// kernel is latency-bound. Channel-split doubles wave count (block
// retire/launch pipelining), halves per-thread texel payload and VGPRs.
// Per thread: 2 meta loads (pair-duplicated, coalescer merges), 4 uint4
// texel loads, 8 NT dword stores (each instr covers two FULL 128B lines:
// 32 px x 4B per plane).
// ---------------------------------------------------------------------------
__device__ inline void acc8p(float2* o2, uint4 t, float w)
{
    const unsigned* p = (const unsigned*)&t;
#pragma unroll
    for (int j = 0; j < 4; ++j) {
        const float2 fp = __half22float2(*(const __half2*)&p[j]);
        o2[j].x += fp.x * w;
        o2[j].y += fp.y * w;
    }
}

__global__ __launch_bounds__(256)
void gather_kernel(const __half* __restrict__ y,
                   const int*    __restrict__ quad,
                   const float2* __restrict__ uv2,
                   float* __restrict__ out)
{
    const int gid = blockIdx.x * 256 + threadIdx.x;
    const int pix = gid >> 1;            // pixel
    const int h   = gid & 1;             // channel half: ch 8h .. 8h+7

    const vf2 tv = __builtin_nontemporal_load((const vf2*)&uv2[pix]);
    const int f  = __builtin_nontemporal_load(&quad[pix]);

    const float u = tv.x;
    const float v = tv.y;

    int u0 = (int)floorf(u);
    int v0 = (int)floorf(v);
    u0 = min(max(u0, 0), ND - 2);
    v0 = min(max(v0, 0), ND - 2);

    // This thread's 4 texels' channel-half: 4 x 16 B.
    const size_t base = (((size_t)f * ND + v0) * ND + u0) * BC;
    const uint4* r0 = (const uint4*)(y + base) + h;                    // (v0,  *)
    const uint4* r1 = (const uint4*)(y + base + (size_t)ND * BC) + h;  // (v0+1,*)
    const uint4 ta = r0[0];   // (v0,  u0)   ch 8h..8h+7
    const uint4 tb = r0[2];   // (v0,  u0+1)
    const uint4 tc = r1[0];   // (v0+1,u0)
    const uint4 td = r1[2];   // (v0+1,u0+1)

    const float du = u - (float)u0;
    const float dv = v - (float)v0;
    const float w00 = (1.0f - du) * (1.0f - dv);
    const float w01 = du * (1.0f - dv);
    const float w10 = (1.0f - du) * dv;
    const float w11 = du * dv;

    float2 o2[4];
#pragma unroll
    for (int j = 0; j < 4; ++j) o2[j] = make_float2(0.0f, 0.0f);

    acc8p(o2, ta, w00);
    acc8p(o2, tb, w01);
    acc8p(o2, tc, w10);
    acc8p(o2, td, w11);

    // 8 NT dword stores; per instruction the wave covers planes j and j+8
    // with one full 128 B line each (32 consecutive px x 4 B).
    const float* o = (const float*)o2;
    float* op = out + (size_t)(8 * h) * HW + pix;
#pragma unroll
    for (int j = 0; j < 8; ++j)
        __builtin_nontemporal_store(o[j], op + (size_t)j * HW);
}

// ---------------------------------------------------------------------------
// Fallback: used only if ws_size can't hold the repacked texture.
// ---------------------------------------------------------------------------
__global__ __launch_bounds__(256)
void resample_fallback_kernel(const float* __restrict__ x,
                              const int*   __restrict__ quad,
                              const float2* __restrict__ uv2,
                              float* __restrict__ out)
{
    const int gid = blockIdx.x * 256 + threadIdx.x;
    const int pix = gid & (HW - 1);
    const int bc  = gid >> HW_SHIFT;

    const float2 t = uv2[pix];
    const int    f = quad[pix];

    const float u = t.x;
    const float v = t.y;

    int u0 = (int)floorf(u);
    int v0 = (int)floorf(v);
    u0 = min(max(u0, 0), ND - 2);
    v0 = min(max(v0, 0), ND - 2);

    const float du = u - (float)u0;
    const float dv = v - (float)v0;

    const float w00 = (1.0f - du) * (1.0f - dv);
    const float w01 = du * (1.0f - dv);
    const float w10 = (1.0f - du) * dv;
    const float w11 = du * dv;

    const float* p = x + ((size_t)bc * FD + (size_t)f) * NN + v0 * ND + u0;
    out[gid] = p[0] * w00 + p[1] * w01 + p[ND] * w10 + p[ND + 1] * w11;
}

extern "C" void kernel_launch(void* const* d_in, const int* in_sizes, int n_in,
                              void* d_out, int out_size, void* d_ws, size_t ws_size,
                              hipStream_t stream)
{
    const float*  x    = (const float*)d_in[0];
    const int*    quad = (const int*)d_in[1];
    const float2* uv2  = (const float2*)d_in[2];
    float*        out  = (float*)d_out;

    if (ws_size >= YH_BYTES) {
        __half* y = (__half*)d_ws;
        repack_kernel<<<FD * ND / 2, 256, 0, stream>>>(x, y);              // 5120 blocks
        gather_kernel<<<2 * HW / 256, 256, 0, stream>>>(y, quad, uv2, out); // 4096 blocks
    } else {
        const int total = BC * HW;
        resample_fallback_kernel<<<total / 256, 256, 0, stream>>>(x, quad, uv2, out);
    }
}